// Round 1
// baseline (580.130 us; speedup 1.0000x reference)
//
#include <hip/hip_runtime.h>

// CausalAffineAutoregFlow — MI355X bf16-MFMA implementation.
//
// Transposed compute: per wave, N=16 batch rows, M=neurons (7 tiles of 16,
// NH=100 padded to 112), K chunks of 32 via mfma_f32_16x16x32_bf16.
// D layout (col=lane&15=batch, row=4*(lane>>4)+reg=neuron) feeds the next
// layer's B operand directly under slot-permutation sigma, compensated in the
// offline weight packing (prepack kernel). No LDS/shuffles between layers.
//
// Slot conventions:
//  - B/x/z/e per-lane slots j=0..7: logical dim = 8*(lane>>4)+j   (sigma0)
//  - H-derived B chunk c slot (G,j): logical neuron 32c+(j>>2)*16+4G+(j&3)
//  - bias folds: b1 at dim-31 slot (x[31]==0 always since C[31][i]==0);
//    b2/b3 at padded neuron k==100 slot (B slot (G=1,j=0) of chunk 3 := 1.0)

typedef __attribute__((ext_vector_type(8))) short short8;
typedef __attribute__((ext_vector_type(4))) float f32x4;
typedef __attribute__((ext_vector_type(4))) unsigned int uint4v;

#define NFRAG_PER_MLP 2496   // u16 19968 / 8
#define WPK_U16 39936
#define MPK_OFF_BYTES 79872  // 39936*2, 16B aligned

__device__ __forceinline__ unsigned int bf16u(float v) {
  unsigned int b = __float_as_uint(v);
  b += 0x7FFFu + ((b >> 16) & 1u);   // RNE round to bf16
  return b >> 16;
}

__device__ __forceinline__ unsigned int pack2(float lo, float hi) {
  return bf16u(lo) | (bf16u(hi) << 16);
}

// Build B-fragment chunk c from 7 accumulator tiles (post-relu).
__device__ __forceinline__ short8 build_B(const f32x4 (&h)[7], int c, bool g1) {
  uint4v u;
  if (c < 3) {
    u.x = pack2(h[2 * c][0], h[2 * c][1]);
    u.y = pack2(h[2 * c][2], h[2 * c][3]);
    u.z = pack2(h[2 * c + 1][0], h[2 * c + 1][1]);
    u.w = pack2(h[2 * c + 1][2], h[2 * c + 1][3]);
  } else {
    u.x = pack2(h[6][0], h[6][1]);
    u.y = pack2(h[6][2], h[6][3]);
    u.z = 0u; u.w = 0u;
    // bias slot: logical k==100 -> (G==1, j==0) low half := bf16(1.0)
    if (g1) u.x = (u.x & 0xFFFF0000u) | 0x3F80u;
  }
  return __builtin_bit_cast(short8, u);
}

// Full 3-layer MLP (weights pre-packed into A-fragments), returns pre-sigmoid
// scalar valid on lanes 0..15 (batch col = lane&15).
__device__ __forceinline__ float mlp_eval(const short8 (&a1)[7],
                                          const short8 (&a2)[7][4],
                                          const short8 (&a3)[4],
                                          short8 x, bool g1) {
  const f32x4 zz = {0.f, 0.f, 0.f, 0.f};
  f32x4 h1[7];
#pragma unroll
  for (int t = 0; t < 7; ++t)
    h1[t] = __builtin_amdgcn_mfma_f32_16x16x32_bf16(a1[t], x, zz, 0, 0, 0);
#pragma unroll
  for (int t = 0; t < 7; ++t) {
    h1[t][0] = fmaxf(h1[t][0], 0.f);
    h1[t][1] = fmaxf(h1[t][1], 0.f);
    h1[t][2] = fmaxf(h1[t][2], 0.f);
    h1[t][3] = fmaxf(h1[t][3], 0.f);
  }
  f32x4 h2[7];
#pragma unroll
  for (int t = 0; t < 7; ++t) h2[t] = zz;
#pragma unroll
  for (int c = 0; c < 4; ++c) {
    short8 B = build_B(h1, c, g1);
#pragma unroll
    for (int t = 0; t < 7; ++t)
      h2[t] = __builtin_amdgcn_mfma_f32_16x16x32_bf16(a2[t][c], B, h2[t], 0, 0, 0);
  }
#pragma unroll
  for (int t = 0; t < 7; ++t) {
    h2[t][0] = fmaxf(h2[t][0], 0.f);
    h2[t][1] = fmaxf(h2[t][1], 0.f);
    h2[t][2] = fmaxf(h2[t][2], 0.f);
    h2[t][3] = fmaxf(h2[t][3], 0.f);
  }
  f32x4 acc = zz;
#pragma unroll
  for (int c = 0; c < 4; ++c) {
    short8 B = build_B(h2, c, g1);
    acc = __builtin_amdgcn_mfma_f32_16x16x32_bf16(a3[c], B, acc, 0, 0, 0);
  }
  return acc[0];  // row 0 (W3^T single row) on lanes 0..15
}

__device__ __forceinline__ float pick8(int j, const f32x4 &a, const f32x4 &b) {
  float v0 = (j & 1) ? a[1] : a[0];
  float v1 = (j & 1) ? a[3] : a[2];
  float v2 = (j & 1) ? b[1] : b[0];
  float v3 = (j & 1) ? b[3] : b[2];
  float w0 = (j & 2) ? v1 : v0;
  float w1 = (j & 2) ? v3 : v2;
  return (j & 4) ? w1 : w0;
}

// ---------------- prepack: fp32 weights -> packed bf16 A-fragments ----------
__global__ void prepack_kernel(const float *__restrict__ C,
                               const float *__restrict__ sW1, const float *__restrict__ sb1,
                               const float *__restrict__ sW2, const float *__restrict__ sb2,
                               const float *__restrict__ sW3, const float *__restrict__ sb3,
                               const float *__restrict__ tW1, const float *__restrict__ tb1,
                               const float *__restrict__ tW2, const float *__restrict__ tb2,
                               const float *__restrict__ tW3, const float *__restrict__ tb3,
                               unsigned short *__restrict__ wpk,
                               unsigned int *__restrict__ mpk) {
  int gid = blockIdx.x * 256 + threadIdx.x;
  if (gid < WPK_U16) {
    int which = gid / 19968;
    int a = gid % 19968;
    const float *W1 = which ? tW1 : sW1;
    const float *B1 = which ? tb1 : sb1;
    const float *W2 = which ? tW2 : sW2;
    const float *B2 = which ? tb2 : sb2;
    const float *W3 = which ? tW3 : sW3;
    const float *B3 = which ? tb3 : sb3;
    float v = 0.f;
    if (a < 3584) {                 // A1: [t][l][j]
      int t = a >> 9; int rem = a & 511; int l = rem >> 3; int j = rem & 7;
      int m = 16 * t + (l & 15);
      int d = 8 * (l >> 4) + j;
      if (m < 100) {
        if (d == 31) v = B1[m];     // bias via always-zero dim-31 slot
        else v = W1[d * 100 + m];
      }
    } else if (a < 17920) {         // A2: [t][c][l][j]
      int b = a - 3584; int tc = b >> 9; int t = tc >> 2; int c = tc & 3;
      int rem = b & 511; int l = rem >> 3; int j = rem & 7;
      int m = 16 * t + (l & 15);
      int k = 32 * c + (j >> 2) * 16 + 4 * (l >> 4) + (j & 3);
      if (m < 100) {
        if (k < 100) v = W2[k * 100 + m];
        else if (k == 100) v = B2[m];
      }
    } else {                        // A3: [c][l][j] (only m==0 row nonzero)
      int b = a - 17920; int c = b >> 9; int rem = b & 511;
      int l = rem >> 3; int j = rem & 7;
      int m = l & 15;
      int k = 32 * c + (j >> 2) * 16 + 4 * (l >> 4) + (j & 3);
      if (m == 0) {
        if (k < 100) v = W3[k];
        else if (k == 100) v = B3[0];
      }
    }
    wpk[gid] = (unsigned short)bf16u(v);
  } else if (gid < WPK_U16 + 512) { // AND-masks: [i][G][p]
    int idx = gid - WPK_U16;
    int i = idx >> 4;
    int G = (idx >> 2) & 3;
    int p = idx & 3;
    int d0 = 8 * G + 2 * p;
    unsigned int u = 0;
    if (C[d0 * 32 + i] != 0.f) u |= 0x0000FFFFu;
    if (C[(d0 + 1) * 32 + i] != 0.f) u |= 0xFFFF0000u;
    mpk[idx] = u;
  }
}

// ---------------- main kernel: one wave, 16 batch rows per tile -------------
__global__ __launch_bounds__(64, 1) void flow_main(
    const float *__restrict__ e, const unsigned short *__restrict__ wpk,
    const unsigned int *__restrict__ mpk, float *__restrict__ out) {
  const int lane = threadIdx.x;
  const int G = lane >> 4;
  const int bl = lane & 15;
  const bool g1 = (G == 1);
  const bool g3 = (G == 3);

  __shared__ __align__(16) unsigned int msk[512];
  {
    const uint4v *s = (const uint4v *)mpk;
    uint4v *d = (uint4v *)msk;
    d[lane] = s[lane];
    d[lane + 64] = s[lane + 64];
  }

  const short8 *w = (const short8 *)wpk;
  short8 a1s[7], a2s[7][4], a3s[4];
  short8 a1t[7], a2t[7][4], a3t[4];
#pragma unroll
  for (int t = 0; t < 7; ++t) a1s[t] = w[t * 64 + lane];
#pragma unroll
  for (int t = 0; t < 7; ++t)
#pragma unroll
    for (int c = 0; c < 4; ++c) a2s[t][c] = w[448 + (t * 4 + c) * 64 + lane];
#pragma unroll
  for (int c = 0; c < 4; ++c) a3s[c] = w[2240 + c * 64 + lane];
#pragma unroll
  for (int t = 0; t < 7; ++t) a1t[t] = w[NFRAG_PER_MLP + t * 64 + lane];
#pragma unroll
  for (int t = 0; t < 7; ++t)
#pragma unroll
    for (int c = 0; c < 4; ++c)
      a2t[t][c] = w[NFRAG_PER_MLP + 448 + (t * 4 + c) * 64 + lane];
#pragma unroll
  for (int c = 0; c < 4; ++c) a3t[c] = w[NFRAG_PER_MLP + 2240 + c * 64 + lane];

#pragma unroll 1
  for (int rep = 0; rep < 4; ++rep) {
    const long base = ((long)blockIdx.x * 4 + rep) * 16;
    const float *ep = e + (base + bl) * 32 + G * 8;
    f32x4 e0 = *(const f32x4 *)ep;
    f32x4 e1 = *(const f32x4 *)(ep + 4);
    unsigned int z0 = 0, z1 = 0, z2 = 0, z3 = 0;  // z packed bf16, slots 0..7
    float ld = 0.f;
    uint4v m = *(const uint4v *)&msk[G * 4];  // mask for step 0

#pragma unroll 1
    for (int i = 0; i < 32; ++i) {
      uint4v mn = *(const uint4v *)&msk[((i + 1) & 31) * 16 + G * 4];  // prefetch
      unsigned int x0 = z0 & m.x, x1 = z1 & m.y, x2 = z2 & m.z, x3 = z3 & m.w;
      if (g3) x3 = (x3 & 0x0000FFFFu) | 0x3F800000u;  // slot31 := 1.0 (b1 fold)
      uint4v xu; xu.x = x0; xu.y = x1; xu.z = x2; xu.w = x3;
      short8 x = __builtin_bit_cast(short8, xu);

      float sp = mlp_eval(a1s, a2s, a3s, x, g1);
      float tp = mlp_eval(a1t, a2t, a3t, x, g1);
      float sv = __fdividef(1.f, 1.f + __expf(-sp));
      float tv = __fdividef(1.f, 1.f + __expf(-tp));
      float s_all = __shfl(sv, bl, 64);  // broadcast row value from lanes 0..15
      float t_all = __shfl(tv, bl, 64);
      ld += s_all;

      float es = pick8(i & 7, e0, e1);
      float zn = __expf(s_all) * es + t_all;
      unsigned int zb = bf16u(zn);
      int hi = i & 1;
      int p = (i >> 1) & 3;
      bool tg = (G == (i >> 3));
      unsigned int i0 = hi ? ((z0 & 0x0000FFFFu) | (zb << 16)) : ((z0 & 0xFFFF0000u) | zb);
      unsigned int i1 = hi ? ((z1 & 0x0000FFFFu) | (zb << 16)) : ((z1 & 0xFFFF0000u) | zb);
      unsigned int i2 = hi ? ((z2 & 0x0000FFFFu) | (zb << 16)) : ((z2 & 0xFFFF0000u) | zb);
      unsigned int i3 = hi ? ((z3 & 0x0000FFFFu) | (zb << 16)) : ((z3 & 0xFFFF0000u) | zb);
      z0 = (tg && p == 0) ? i0 : z0;
      z1 = (tg && p == 1) ? i1 : z1;
      z2 = (tg && p == 2) ? i2 : z2;
      z3 = (tg && p == 3) ? i3 : z3;
      m = mn;
    }

    float *zo = out + (base + bl) * 32 + G * 8;
    f32x4 o0, o1;
    o0[0] = __uint_as_float(z0 << 16);
    o0[1] = __uint_as_float(z0 & 0xFFFF0000u);
    o0[2] = __uint_as_float(z1 << 16);
    o0[3] = __uint_as_float(z1 & 0xFFFF0000u);
    o1[0] = __uint_as_float(z2 << 16);
    o1[1] = __uint_as_float(z2 & 0xFFFF0000u);
    o1[2] = __uint_as_float(z3 << 16);
    o1[3] = __uint_as_float(z3 & 0xFFFF0000u);
    *(f32x4 *)zo = o0;
    *(f32x4 *)(zo + 4) = o1;
    if (lane < 16) out[(long)131072 * 32 + base + bl] = ld;
  }
}

extern "C" void kernel_launch(void *const *d_in, const int *in_sizes, int n_in,
                              void *d_out, int out_size, void *d_ws, size_t ws_size,
                              hipStream_t stream) {
  const float *e  = (const float *)d_in[0];
  const float *C  = (const float *)d_in[1];
  const float *sW1 = (const float *)d_in[2];
  const float *sb1 = (const float *)d_in[3];
  const float *sW2 = (const float *)d_in[4];
  const float *sb2 = (const float *)d_in[5];
  const float *sW3 = (const float *)d_in[6];
  const float *sb3 = (const float *)d_in[7];
  const float *tW1 = (const float *)d_in[8];
  const float *tb1 = (const float *)d_in[9];
  const float *tW2 = (const float *)d_in[10];
  const float *tb2 = (const float *)d_in[11];
  const float *tW3 = (const float *)d_in[12];
  const float *tb3 = (const float *)d_in[13];

  unsigned short *wpk = (unsigned short *)d_ws;
  unsigned int *mpk = (unsigned int *)((char *)d_ws + MPK_OFF_BYTES);
  float *out = (float *)d_out;

  prepack_kernel<<<dim3(159), dim3(256), 0, stream>>>(
      C, sW1, sb1, sW2, sb2, sW3, sb3, tW1, tb1, tW2, tb2, tW3, tb3, wpk, mpk);
  flow_main<<<dim3(2048), dim3(64), 0, stream>>>(e, wpk, mpk, out);
}

// Round 2
// 334.386 us; speedup vs baseline: 1.7349x; 1.7349x over previous
//
#include <hip/hip_runtime.h>

// CausalAffineAutoregFlow — MI355X bf16-MFMA implementation, round 2.
//
// Transposed compute: per wave, N=16 batch rows, M=neurons (7 tiles of 16,
// NH=100 padded to 112), K chunks of 32 via mfma_f32_16x16x32_bf16.
// D layout (col=lane&15=batch, row=4*(lane>>4)+reg=neuron) feeds the next
// layer's B operand directly under slot-permutation sigma, compensated in the
// offline weight packing (prepack kernel). No LDS/shuffles between layers.
//
// R2 changes: v_cvt_pk_bf16_f32 packing (1 inst/pair), W3 replicated across
// all 16 rows (removes __shfl broadcasts), inner loop unrolled x8 (static
// slot/half selects and e-element picks).
//
// Slot conventions:
//  - B/x/z/e per-lane slots j=0..7: logical dim = 8*(lane>>4)+j
//  - H-derived B chunk c slot (G,j): logical neuron 32c+(j>>2)*16+4G+(j&3)
//  - bias folds: b1 at dim-31 slot (x[31]==0 always since C[31][i]==0);
//    b2/b3 at padded neuron k==100 slot (B slot (G=1,j=0) of chunk 3 := 1.0)

typedef __attribute__((ext_vector_type(8))) short short8;
typedef __attribute__((ext_vector_type(4))) float f32x4;
typedef __attribute__((ext_vector_type(4))) unsigned int uint4v;

#define NFRAG_PER_MLP 2496   // u16 19968 / 8
#define WPK_U16 39936
#define MPK_OFF_BYTES 79872  // 39936*2, 16B aligned

__device__ __forceinline__ unsigned int bf16u(float v) {
  unsigned int b = __float_as_uint(v);
  b += 0x7FFFu + ((b >> 16) & 1u);   // RNE round to bf16
  return b >> 16;
}

// One-instruction packed f32->bf16x2 (lo = src0, hi = src1), RNE.
__device__ __forceinline__ unsigned int cvtpk(float lo, float hi) {
  unsigned int r;
  asm("v_cvt_pk_bf16_f32 %0, %1, %2" : "=v"(r) : "v"(lo), "v"(hi));
  return r;
}

// Build B-fragment chunk c from 7 accumulator tiles (post-relu).
__device__ __forceinline__ short8 build_B(const f32x4 (&h)[7], int c, bool g1) {
  uint4v u;
  if (c < 3) {
    u.x = cvtpk(h[2 * c][0], h[2 * c][1]);
    u.y = cvtpk(h[2 * c][2], h[2 * c][3]);
    u.z = cvtpk(h[2 * c + 1][0], h[2 * c + 1][1]);
    u.w = cvtpk(h[2 * c + 1][2], h[2 * c + 1][3]);
  } else {
    // bias slot: logical k==100 -> (G==1, j==0) := 1.0 (pre-cvt float select)
    float v0 = g1 ? 1.0f : h[6][0];
    u.x = cvtpk(v0, h[6][1]);
    u.y = cvtpk(h[6][2], h[6][3]);
    u.z = 0u; u.w = 0u;
  }
  return __builtin_bit_cast(short8, u);
}

// Full 3-layer MLP (weights pre-packed into A-fragments), returns pre-sigmoid
// scalar valid on ALL lanes (W3 replicated across rows in prepack).
__device__ __forceinline__ float mlp_eval(const short8 (&a1)[7],
                                          const short8 (&a2)[7][4],
                                          const short8 (&a3)[4],
                                          short8 x, bool g1) {
  const f32x4 zz = {0.f, 0.f, 0.f, 0.f};
  f32x4 h1[7];
#pragma unroll
  for (int t = 0; t < 7; ++t)
    h1[t] = __builtin_amdgcn_mfma_f32_16x16x32_bf16(a1[t], x, zz, 0, 0, 0);
#pragma unroll
  for (int t = 0; t < 7; ++t) {
    h1[t][0] = fmaxf(h1[t][0], 0.f);
    h1[t][1] = fmaxf(h1[t][1], 0.f);
    h1[t][2] = fmaxf(h1[t][2], 0.f);
    h1[t][3] = fmaxf(h1[t][3], 0.f);
  }
  f32x4 h2[7];
#pragma unroll
  for (int t = 0; t < 7; ++t) h2[t] = zz;
#pragma unroll
  for (int c = 0; c < 4; ++c) {
    short8 B = build_B(h1, c, g1);
#pragma unroll
    for (int t = 0; t < 7; ++t)
      h2[t] = __builtin_amdgcn_mfma_f32_16x16x32_bf16(a2[t][c], B, h2[t], 0, 0, 0);
  }
#pragma unroll
  for (int t = 0; t < 7; ++t) {
    h2[t][0] = fmaxf(h2[t][0], 0.f);
    h2[t][1] = fmaxf(h2[t][1], 0.f);
    h2[t][2] = fmaxf(h2[t][2], 0.f);
    h2[t][3] = fmaxf(h2[t][3], 0.f);
  }
  f32x4 acc = zz;
#pragma unroll
  for (int c = 0; c < 4; ++c) {
    short8 B = build_B(h2, c, g1);
    acc = __builtin_amdgcn_mfma_f32_16x16x32_bf16(a3[c], B, acc, 0, 0, 0);
  }
  return acc[0];  // replicated row -> valid on all 64 lanes
}

// ---------------- prepack: fp32 weights -> packed bf16 A-fragments ----------
__global__ void prepack_kernel(const float *__restrict__ C,
                               const float *__restrict__ sW1, const float *__restrict__ sb1,
                               const float *__restrict__ sW2, const float *__restrict__ sb2,
                               const float *__restrict__ sW3, const float *__restrict__ sb3,
                               const float *__restrict__ tW1, const float *__restrict__ tb1,
                               const float *__restrict__ tW2, const float *__restrict__ tb2,
                               const float *__restrict__ tW3, const float *__restrict__ tb3,
                               unsigned short *__restrict__ wpk,
                               unsigned int *__restrict__ mpk) {
  int gid = blockIdx.x * 256 + threadIdx.x;
  if (gid < WPK_U16) {
    int which = gid / 19968;
    int a = gid % 19968;
    const float *W1 = which ? tW1 : sW1;
    const float *B1 = which ? tb1 : sb1;
    const float *W2 = which ? tW2 : sW2;
    const float *B2 = which ? tb2 : sb2;
    const float *W3 = which ? tW3 : sW3;
    const float *B3 = which ? tb3 : sb3;
    float v = 0.f;
    if (a < 3584) {                 // A1: [t][l][j]
      int t = a >> 9; int rem = a & 511; int l = rem >> 3; int j = rem & 7;
      int m = 16 * t + (l & 15);
      int d = 8 * (l >> 4) + j;
      if (m < 100) {
        if (d == 31) v = B1[m];     // bias via always-zero dim-31 slot
        else v = W1[d * 100 + m];
      }
    } else if (a < 17920) {         // A2: [t][c][l][j]
      int b = a - 3584; int tc = b >> 9; int t = tc >> 2; int c = tc & 3;
      int rem = b & 511; int l = rem >> 3; int j = rem & 7;
      int m = 16 * t + (l & 15);
      int k = 32 * c + (j >> 2) * 16 + 4 * (l >> 4) + (j & 3);
      if (m < 100) {
        if (k < 100) v = W2[k * 100 + m];
        else if (k == 100) v = B2[m];
      }
    } else {                        // A3: [c][l][j], REPLICATED across rows m
      int b = a - 17920; int c = b >> 9; int rem = b & 511;
      int l = rem >> 3; int j = rem & 7;
      int k = 32 * c + (j >> 2) * 16 + 4 * (l >> 4) + (j & 3);
      (void)l;
      if (k < 100) v = W3[k];
      else if (k == 100) v = B3[0];
    }
    wpk[gid] = (unsigned short)bf16u(v);
  } else if (gid < WPK_U16 + 512) { // AND-masks: [i][G][p]
    int idx = gid - WPK_U16;
    int i = idx >> 4;
    int G = (idx >> 2) & 3;
    int p = idx & 3;
    int d0 = 8 * G + 2 * p;
    unsigned int u = 0;
    if (C[d0 * 32 + i] != 0.f) u |= 0x0000FFFFu;
    if (C[(d0 + 1) * 32 + i] != 0.f) u |= 0xFFFF0000u;
    mpk[idx] = u;
  }
}

// ---------------- main kernel: one wave, 16 batch rows per tile -------------
__global__ __launch_bounds__(64, 1) void flow_main(
    const float *__restrict__ e, const unsigned short *__restrict__ wpk,
    const unsigned int *__restrict__ mpk, float *__restrict__ out) {
  const int lane = threadIdx.x;
  const int G = lane >> 4;
  const int bl = lane & 15;
  const bool g1 = (G == 1);
  const bool g3 = (G == 3);

  __shared__ __align__(16) unsigned int msk[512];
  {
    const uint4v *s = (const uint4v *)mpk;
    uint4v *d = (uint4v *)msk;
    d[lane] = s[lane];
    d[lane + 64] = s[lane + 64];
  }

  const short8 *w = (const short8 *)wpk;
  short8 a1s[7], a2s[7][4], a3s[4];
  short8 a1t[7], a2t[7][4], a3t[4];
#pragma unroll
  for (int t = 0; t < 7; ++t) a1s[t] = w[t * 64 + lane];
#pragma unroll
  for (int t = 0; t < 7; ++t)
#pragma unroll
    for (int c = 0; c < 4; ++c) a2s[t][c] = w[448 + (t * 4 + c) * 64 + lane];
#pragma unroll
  for (int c = 0; c < 4; ++c) a3s[c] = w[2240 + c * 64 + lane];
#pragma unroll
  for (int t = 0; t < 7; ++t) a1t[t] = w[NFRAG_PER_MLP + t * 64 + lane];
#pragma unroll
  for (int t = 0; t < 7; ++t)
#pragma unroll
    for (int c = 0; c < 4; ++c)
      a2t[t][c] = w[NFRAG_PER_MLP + 448 + (t * 4 + c) * 64 + lane];
#pragma unroll
  for (int c = 0; c < 4; ++c) a3t[c] = w[NFRAG_PER_MLP + 2240 + c * 64 + lane];

#pragma unroll 1
  for (int rep = 0; rep < 4; ++rep) {
    const long base = ((long)blockIdx.x * 4 + rep) * 16;
    const float *ep = e + (base + bl) * 32 + G * 8;
    f32x4 e0 = *(const f32x4 *)ep;
    f32x4 e1 = *(const f32x4 *)(ep + 4);
    unsigned int z0 = 0, z1 = 0, z2 = 0, z3 = 0;  // z packed bf16, slots 0..7
    float ld = 0.f;
    uint4v m = *(const uint4v *)&msk[G * 4];  // mask for step 0

#pragma unroll 1
    for (int i8 = 0; i8 < 4; ++i8) {
      const bool tg = (G == i8);  // hoisted target-group predicate
#pragma unroll
      for (int u = 0; u < 8; ++u) {
        const int i = i8 * 8 + u;
        uint4v mn = *(const uint4v *)&msk[((i + 1) & 31) * 16 + G * 4];
        unsigned int x0 = z0 & m.x, x1 = z1 & m.y, x2 = z2 & m.z, x3 = z3 & m.w;
        if (g3) x3 = (x3 & 0x0000FFFFu) | 0x3F800000u;  // slot31 := 1.0
        uint4v xu; xu.x = x0; xu.y = x1; xu.z = x2; xu.w = x3;
        short8 x = __builtin_bit_cast(short8, xu);

        float sp = mlp_eval(a1s, a2s, a3s, x, g1);
        float tp = mlp_eval(a1t, a2t, a3t, x, g1);
        float sv = __fdividef(1.f, 1.f + __expf(-sp));
        float tv = __fdividef(1.f, 1.f + __expf(-tp));
        ld += sv;

        float es = (u < 4) ? e0[u] : e1[u - 4];   // static under unroll
        float zn = __expf(sv) * es + tv;
        unsigned int r = cvtpk(zn, zn);           // lo & hi both bf16(zn)
        const int p = (u >> 1) & 3;
        const bool hi = (u & 1) != 0;
        unsigned int mrg;
        if (p == 0) {
          mrg = hi ? ((z0 & 0x0000FFFFu) | (r & 0xFFFF0000u))
                   : ((z0 & 0xFFFF0000u) | (r & 0x0000FFFFu));
          z0 = tg ? mrg : z0;
        } else if (p == 1) {
          mrg = hi ? ((z1 & 0x0000FFFFu) | (r & 0xFFFF0000u))
                   : ((z1 & 0xFFFF0000u) | (r & 0x0000FFFFu));
          z1 = tg ? mrg : z1;
        } else if (p == 2) {
          mrg = hi ? ((z2 & 0x0000FFFFu) | (r & 0xFFFF0000u))
                   : ((z2 & 0xFFFF0000u) | (r & 0x0000FFFFu));
          z2 = tg ? mrg : z2;
        } else {
          mrg = hi ? ((z3 & 0x0000FFFFu) | (r & 0xFFFF0000u))
                   : ((z3 & 0xFFFF0000u) | (r & 0x0000FFFFu));
          z3 = tg ? mrg : z3;
        }
        m = mn;
      }
    }

    float *zo = out + (base + bl) * 32 + G * 8;
    f32x4 o0, o1;
    o0[0] = __uint_as_float(z0 << 16);
    o0[1] = __uint_as_float(z0 & 0xFFFF0000u);
    o0[2] = __uint_as_float(z1 << 16);
    o0[3] = __uint_as_float(z1 & 0xFFFF0000u);
    o1[0] = __uint_as_float(z2 << 16);
    o1[1] = __uint_as_float(z2 & 0xFFFF0000u);
    o1[2] = __uint_as_float(z3 << 16);
    o1[3] = __uint_as_float(z3 & 0xFFFF0000u);
    *(f32x4 *)zo = o0;
    *(f32x4 *)(zo + 4) = o1;
    if (lane < 16) out[(long)131072 * 32 + base + bl] = ld;
  }
}

extern "C" void kernel_launch(void *const *d_in, const int *in_sizes, int n_in,
                              void *d_out, int out_size, void *d_ws, size_t ws_size,
                              hipStream_t stream) {
  const float *e  = (const float *)d_in[0];
  const float *C  = (const float *)d_in[1];
  const float *sW1 = (const float *)d_in[2];
  const float *sb1 = (const float *)d_in[3];
  const float *sW2 = (const float *)d_in[4];
  const float *sb2 = (const float *)d_in[5];
  const float *sW3 = (const float *)d_in[6];
  const float *sb3 = (const float *)d_in[7];
  const float *tW1 = (const float *)d_in[8];
  const float *tb1 = (const float *)d_in[9];
  const float *tW2 = (const float *)d_in[10];
  const float *tb2 = (const float *)d_in[11];
  const float *tW3 = (const float *)d_in[12];
  const float *tb3 = (const float *)d_in[13];

  unsigned short *wpk = (unsigned short *)d_ws;
  unsigned int *mpk = (unsigned int *)((char *)d_ws + MPK_OFF_BYTES);
  float *out = (float *)d_out;

  prepack_kernel<<<dim3(159), dim3(256), 0, stream>>>(
      C, sW1, sb1, sW2, sb2, sW3, sb3, tW1, tb1, tW2, tb2, tW3, tb3, wpk, mpk);
  flow_main<<<dim3(2048), dim3(64), 0, stream>>>(e, wpk, mpk, out);
}